// Round 2
// baseline (7588.326 us; speedup 1.0000x reference)
//
#include <hip/hip_runtime.h>

// ---------------------------------------------------------------------------
// GatedLSTM: B=64, S=512, I=1024, H=1024, fp32 in/out, bf16 MFMA compute.
// i-gate is computed-but-unused in the reference -> skipped entirely.
//
// Pipeline (all on `stream`):
//   1) cvt6       : W_f/W_o/W_c, U_f/U_o/U_c  fp32 -> bf16 (ws), one kernel
//   2) memsetAsync: h double-buffer + barrier flags -> 0
//   3) gemm_xw    : G_g[s][b][h] = x @ W_g^T + b_g  (bf16, time-major)
//   4) lstm_scan  : 512-step recurrence, 64 co-resident WGs, U in VGPRs,
//                   flag-array grid barrier (parallel release stores +
//                   relaxed polls + one acquire fence per step).
// ---------------------------------------------------------------------------

typedef __attribute__((ext_vector_type(4))) float f32x4;
typedef __attribute__((ext_vector_type(8))) __bf16 bf16x8;

#define S_LEN 512
#define B_SZ  64
#define H_SZ  1024
#define I_SZ  1024
#define NWG   64

// ---- workspace layout (bytes) ----
#define OFF_WF  0
#define OFF_WO  2097152
#define OFF_WC  4194304
#define OFF_UF  6291456
#define OFF_UO  8388608
#define OFF_UC  10485760
#define OFF_GF  12582912
#define OFF_GO  79691776
#define OFF_GC  146800640
#define OFF_HB  213909504   // 2 * 64 * 1024 * 2 bytes = 262144
#define OFF_FLG 214171648   // 64 flags * 128B stride = 8192 bytes
#define FLG_STRIDE 32       // in u32 units (128 bytes)

__device__ __forceinline__ unsigned short f2bf(float f) {
  unsigned u = __float_as_uint(f);
  u += 0x7FFFu + ((u >> 16) & 1u);   // RNE (inputs finite)
  return (unsigned short)(u >> 16);
}
__device__ __forceinline__ float bf2f(unsigned short h) {
  return __uint_as_float(((unsigned)h) << 16);
}
__device__ __forceinline__ unsigned pack2(float lo, float hi) {
  return (unsigned)f2bf(lo) | ((unsigned)f2bf(hi) << 16);
}
__device__ __forceinline__ float sigmoid_f(float x) {
  return 1.f / (1.f + __expf(-x));
}
__device__ __forceinline__ float tanh_f(float x) {
  float xc = fminf(fmaxf(x, -15.f), 15.f);
  float e = __expf(-2.f * xc);       // in (0, e^30], finite
  return (1.f - e) / (1.f + e);
}

// ---------------------------------------------------------------------------
// Six fp32->bf16 converts in one launch. grid (128, 6), 256 thr.
// ---------------------------------------------------------------------------
__global__ __launch_bounds__(256) void cvt6(
    const float4* __restrict__ s0, const float4* __restrict__ s1,
    const float4* __restrict__ s2, const float4* __restrict__ s3,
    const float4* __restrict__ s4, const float4* __restrict__ s5,
    ushort4* __restrict__ d0, ushort4* __restrict__ d1,
    ushort4* __restrict__ d2, ushort4* __restrict__ d3,
    ushort4* __restrict__ d4, ushort4* __restrict__ d5, int n4) {
  const float4* in; ushort4* out;
  switch (blockIdx.y) {
    case 0: in = s0; out = d0; break;
    case 1: in = s1; out = d1; break;
    case 2: in = s2; out = d2; break;
    case 3: in = s3; out = d3; break;
    case 4: in = s4; out = d4; break;
    default: in = s5; out = d5; break;
  }
  int i = blockIdx.x * 256 + threadIdx.x;
  const int stride = gridDim.x * 256;
  for (; i < n4; i += stride) {
    float4 v = in[i];
    ushort4 o;
    o.x = f2bf(v.x); o.y = f2bf(v.y); o.z = f2bf(v.z); o.w = f2bf(v.w);
    out[i] = o;
  }
}

// ---------------------------------------------------------------------------
// G[s*64+b][j] = sum_k x[b*512+s][k] * W[j][k] + bias[j]   (bf16 out)
// 128x128 tile, BK=32, 4 waves (2x2), reg-staged LDS, m97-style 2-barrier loop.
// grid: (8, 256, 3)  z selects gate.
// ---------------------------------------------------------------------------
__global__ __launch_bounds__(256) void gemm_xw(
    const float* __restrict__ Xf,              // [32768][1024] fp32
    const unsigned short* __restrict__ W0,
    const unsigned short* __restrict__ W1,
    const unsigned short* __restrict__ W2,
    const float* __restrict__ bias0,
    const float* __restrict__ bias1,
    const float* __restrict__ bias2,
    unsigned short* __restrict__ G0,
    unsigned short* __restrict__ G1,
    unsigned short* __restrict__ G2)
{
  const int z = blockIdx.z;
  const unsigned short* W = (z == 0) ? W0 : (z == 1) ? W1 : W2;
  const float* bias        = (z == 0) ? bias0 : (z == 1) ? bias1 : bias2;
  unsigned short* G        = (z == 0) ? G0 : (z == 1) ? G1 : G2;

  const int m0 = blockIdx.y * 128;
  const int n0 = blockIdx.x * 128;
  const int tid = threadIdx.x;
  const int w = tid >> 6, l = tid & 63;
  const int lj = l & 15, lk = l >> 4;
  const int wm = w >> 1, wn = w & 1;

  __shared__ alignas(16) unsigned short As[128 * 32];  // 8 KB
  __shared__ alignas(16) unsigned short Bs[128 * 32];  // 8 KB

  f32x4 acc[4][4];
#pragma unroll
  for (int a = 0; a < 4; ++a)
#pragma unroll
    for (int q = 0; q < 4; ++q) acc[a][q] = (f32x4){0.f, 0.f, 0.f, 0.f};

  const int o1 = tid * 16;        // byte offset of 16B chunk #1 in tile
  const int o2 = o1 + 4096;       // chunk #2
  const int r1 = o1 >> 6, c1 = (o1 & 63) >> 1;   // row, elem-offset
  const int r2 = o2 >> 6, c2 = (o2 & 63) >> 1;

  for (int kt = 0; kt < I_SZ; kt += 32) {
    const float* xa = Xf + (size_t)(m0 + r1) * I_SZ + kt + c1;
    const float* xb = Xf + (size_t)(m0 + r2) * I_SZ + kt + c2;
    float4 x0 = *(const float4*)xa;
    float4 x1 = *(const float4*)(xa + 4);
    float4 x2 = *(const float4*)xb;
    float4 x3 = *(const float4*)(xb + 4);
    uint4 wv0 = *(const uint4*)(W + (size_t)(n0 + r1) * I_SZ + kt + c1);
    uint4 wv1 = *(const uint4*)(W + (size_t)(n0 + r2) * I_SZ + kt + c2);

    uint4 a0, a1;
    a0.x = pack2(x0.x, x0.y); a0.y = pack2(x0.z, x0.w);
    a0.z = pack2(x1.x, x1.y); a0.w = pack2(x1.z, x1.w);
    a1.x = pack2(x2.x, x2.y); a1.y = pack2(x2.z, x2.w);
    a1.z = pack2(x3.x, x3.y); a1.w = pack2(x3.z, x3.w);

    __syncthreads();
    *(uint4*)((char*)As + o1) = a0;
    *(uint4*)((char*)As + o2) = a1;
    *(uint4*)((char*)Bs + o1) = wv0;
    *(uint4*)((char*)Bs + o2) = wv1;
    __syncthreads();

    bf16x8 af[4], bfg[4];
#pragma unroll
    for (int mi = 0; mi < 4; ++mi)
      af[mi] = *(const bf16x8*)(As + (wm * 64 + mi * 16 + lj) * 32 + lk * 8);
#pragma unroll
    for (int ni = 0; ni < 4; ++ni)
      bfg[ni] = *(const bf16x8*)(Bs + (wn * 64 + ni * 16 + lj) * 32 + lk * 8);
#pragma unroll
    for (int mi = 0; mi < 4; ++mi)
#pragma unroll
      for (int ni = 0; ni < 4; ++ni)
        acc[mi][ni] = __builtin_amdgcn_mfma_f32_16x16x32_bf16(af[mi], bfg[ni], acc[mi][ni], 0, 0, 0);
  }

#pragma unroll
  for (int ni = 0; ni < 4; ++ni) {
    const int j = n0 + wn * 64 + ni * 16 + lj;
    const float bb = bias[j];
#pragma unroll
    for (int mi = 0; mi < 4; ++mi) {
#pragma unroll
      for (int r = 0; r < 4; ++r) {
        const int m = m0 + wm * 64 + mi * 16 + lk * 4 + r;
        const int s = m & (S_LEN - 1);
        const int b = m >> 9;
        G[(size_t)(s * B_SZ + b) * H_SZ + j] = f2bf(acc[mi][ni][r] + bb);
      }
    }
  }
}

// ---------------------------------------------------------------------------
// Recurrent scan. 64 WGs x 256 threads, 1 WG/CU -> co-resident. WG wg owns
// H-columns [wg*16, wg*16+16) for 3 gates; wave w owns batch rows [16w,16w+16).
// U-slices in VGPRs. c-state in registers. h double-buffered in ws (bf16).
// Flag-array grid barrier: parallel release stores to per-WG 128B-strided
// flags, wave0 relaxed polls + single acquire fence per step.
// ---------------------------------------------------------------------------
__global__ __launch_bounds__(256, 1) void lstm_scan(
    const unsigned short* __restrict__ Gf,
    const unsigned short* __restrict__ Go,
    const unsigned short* __restrict__ Gc,
    const unsigned short* __restrict__ Uf,
    const unsigned short* __restrict__ Uo,
    const unsigned short* __restrict__ Uc,
    unsigned short* __restrict__ hbuf,   // [2][64][1024] bf16 (zeroed)
    float* __restrict__ out,             // [64][512][1024] ++ h[64][1024] ++ c[64][1024]
    unsigned* __restrict__ flags)        // [64] stride 32 u32 (zeroed)
{
  const int wg = blockIdx.x;          // 0..63
  const int j0 = wg * 16;
  const int tid = threadIdx.x;
  const int w = tid >> 6, l = tid & 63;
  const int lj = l & 15, lk = l >> 4;
  const int j = j0 + lj;              // this lane's output column
  const int brow0 = w * 16 + lk * 4;  // D rows base (batch)

  // ---- preload U fragments into registers: B[k][n] = U[j][k] ----
  bf16x8 bfr[3][32];
  {
    const unsigned short* Ur = Uf + (size_t)j * H_SZ + lk * 8;
#pragma unroll
    for (int ks = 0; ks < 32; ++ks) bfr[0][ks] = *(const bf16x8*)(Ur + ks * 32);
    Ur = Uo + (size_t)j * H_SZ + lk * 8;
#pragma unroll
    for (int ks = 0; ks < 32; ++ks) bfr[1][ks] = *(const bf16x8*)(Ur + ks * 32);
    Ur = Uc + (size_t)j * H_SZ + lk * 8;
#pragma unroll
    for (int ks = 0; ks < 32; ++ks) bfr[2][ks] = *(const bf16x8*)(Ur + ks * 32);
  }

  float cst[4] = {0.f, 0.f, 0.f, 0.f};

  float gf[4], go_[4], gc_[4];
#pragma unroll
  for (int r = 0; r < 4; ++r) {
    const size_t gi = (size_t)(brow0 + r) * H_SZ + j;     // t = 0
    gf[r] = bf2f(Gf[gi]); go_[r] = bf2f(Go[gi]); gc_[r] = bf2f(Gc[gi]);
  }

  const size_t hoff = (size_t)B_SZ * S_LEN * H_SZ;        // 33554432
  const size_t coff = hoff + (size_t)B_SZ * H_SZ;

#pragma unroll 1
  for (int t = 0; t < S_LEN; ++t) {
    const unsigned short* hr = hbuf + (size_t)(t & 1) * (B_SZ * H_SZ)
                                    + (size_t)(w * 16 + lj) * H_SZ + lk * 8;
    unsigned short* hw = hbuf + (size_t)((t + 1) & 1) * (B_SZ * H_SZ);

    f32x4 p0 = {0.f, 0.f, 0.f, 0.f};
    f32x4 p1 = {0.f, 0.f, 0.f, 0.f};
    f32x4 p2 = {0.f, 0.f, 0.f, 0.f};
#pragma unroll
    for (int ks = 0; ks < 32; ++ks) {
      bf16x8 a = *(const bf16x8*)(hr + ks * 32);
      p0 = __builtin_amdgcn_mfma_f32_16x16x32_bf16(a, bfr[0][ks], p0, 0, 0, 0);
      p1 = __builtin_amdgcn_mfma_f32_16x16x32_bf16(a, bfr[1][ks], p1, 0, 0, 0);
      p2 = __builtin_amdgcn_mfma_f32_16x16x32_bf16(a, bfr[2][ks], p2, 0, 0, 0);
    }

    // prefetch next step's gate pre-acts (latency hides under barrier)
    float ngf[4] = {0.f,0.f,0.f,0.f}, ngo[4] = {0.f,0.f,0.f,0.f}, ngc[4] = {0.f,0.f,0.f,0.f};
    if (t + 1 < S_LEN) {
#pragma unroll
      for (int r = 0; r < 4; ++r) {
        const size_t gi = ((size_t)(t + 1) * B_SZ + brow0 + r) * H_SZ + j;
        ngf[r] = bf2f(Gf[gi]); ngo[r] = bf2f(Go[gi]); ngc[r] = bf2f(Gc[gi]);
      }
    }

    // elementwise gates + state update; nt stores keep local L2 clean
#pragma unroll
    for (int r = 0; r < 4; ++r) {
      const int b = brow0 + r;
      const float f = sigmoid_f(p0[r] + gf[r]);
      const float o = sigmoid_f(p1[r] + go_[r]);
      const float tc = tanh_f(p2[r] + gc_[r]);
      cst[r] = f * cst[r] + tc;
      const float h = o * cst[r];
      __builtin_nontemporal_store(h, &out[((size_t)b * S_LEN + t) * H_SZ + j]);
      __builtin_nontemporal_store(f2bf(h), &hw[(size_t)b * H_SZ + j]);
      if (t == S_LEN - 1) {
        out[hoff + (size_t)b * H_SZ + j] = h;
        out[coff + (size_t)b * H_SZ + j] = cst[r];
      }
    }
#pragma unroll
    for (int r = 0; r < 4; ++r) { gf[r] = ngf[r]; go_[r] = ngo[r]; gc_[r] = ngc[r]; }

    // ---- flag-array grid barrier ----
    __syncthreads();                    // all WG stores retired (vmcnt drained)
    if (w == 0) {
      const unsigned target = (unsigned)(t + 1);
      if (l == 0) {
        __builtin_amdgcn_fence(__ATOMIC_RELEASE, "agent");   // writeback dirty L2
        __hip_atomic_store(&flags[wg * FLG_STRIDE], target,
                           __ATOMIC_RELAXED, __HIP_MEMORY_SCOPE_AGENT);
      }
      unsigned v;
      do {
        v = __hip_atomic_load(&flags[l * FLG_STRIDE],
                              __ATOMIC_RELAXED, __HIP_MEMORY_SCOPE_AGENT);
      } while (__any(v < target));
      __builtin_amdgcn_fence(__ATOMIC_ACQUIRE, "agent");     // invalidate stale L2/L1
    }
    __syncthreads();
  }
}

// ---------------------------------------------------------------------------
extern "C" void kernel_launch(void* const* d_in, const int* in_sizes, int n_in,
                              void* d_out, int out_size, void* d_ws, size_t ws_size,
                              hipStream_t stream) {
  const float* x   = (const float*)d_in[0];
  const float* W_f = (const float*)d_in[1];
  const float* U_f = (const float*)d_in[2];
  const float* b_f = (const float*)d_in[3];
  // d_in[4..6] = W_i, U_i, b_i : unused by the reference's output
  const float* W_o = (const float*)d_in[7];
  const float* U_o = (const float*)d_in[8];
  const float* b_o = (const float*)d_in[9];
  const float* W_c = (const float*)d_in[10];
  const float* U_c = (const float*)d_in[11];
  const float* b_c = (const float*)d_in[12];

  char* ws = (char*)d_ws;
  unsigned short* Wfb = (unsigned short*)(ws + OFF_WF);
  unsigned short* Wob = (unsigned short*)(ws + OFF_WO);
  unsigned short* Wcb = (unsigned short*)(ws + OFF_WC);
  unsigned short* Ufb = (unsigned short*)(ws + OFF_UF);
  unsigned short* Uob = (unsigned short*)(ws + OFF_UO);
  unsigned short* Ucb = (unsigned short*)(ws + OFF_UC);
  unsigned short* Gf  = (unsigned short*)(ws + OFF_GF);
  unsigned short* Go  = (unsigned short*)(ws + OFF_GO);
  unsigned short* Gc  = (unsigned short*)(ws + OFF_GC);
  unsigned short* hb  = (unsigned short*)(ws + OFF_HB);
  unsigned* flg       = (unsigned*)(ws + OFF_FLG);

  const int wn4 = (H_SZ * I_SZ) / 4;   // 262144
  dim3 cg(128, 6);
  cvt6<<<cg, 256, 0, stream>>>(
      (const float4*)W_f, (const float4*)W_o, (const float4*)W_c,
      (const float4*)U_f, (const float4*)U_o, (const float4*)U_c,
      (ushort4*)Wfb, (ushort4*)Wob, (ushort4*)Wcb,
      (ushort4*)Ufb, (ushort4*)Uob, (ushort4*)Ucb, wn4);

  // zero h double-buffer + barrier flags (ws is poisoned each call)
  hipMemsetAsync(ws + OFF_HB, 0, 262144 + 8192, stream);

  dim3 gg(8, 256, 3);
  gemm_xw<<<gg, 256, 0, stream>>>(x, Wfb, Wob, Wcb, b_f, b_o, b_c, Gf, Go, Gc);

  lstm_scan<<<NWG, 256, 0, stream>>>(Gf, Go, Gc, Ufb, Uob, Ucb, hb,
                                     (float*)d_out, flg);
}

// Round 3
// 5345.191 us; speedup vs baseline: 1.4197x; 1.4197x over previous
//
#include <hip/hip_runtime.h>

// ---------------------------------------------------------------------------
// GatedLSTM: B=64, S=512, I=1024, H=1024, fp32 in/out, bf16 MFMA compute.
// i-gate is computed-but-unused in the reference -> skipped entirely.
//
//   1) cvt6       : W_f/W_o/W_c, U_f/U_o/U_c  fp32 -> bf16 (ws)
//   2) memsetAsync: h double-buffer + barrier flags -> 0
//   3) gemm_xw    : G_g[s][b][h] = x @ W_g^T + b_g  (bf16, time-major)
//   4) lstm_scan  : 512-step recurrence, 64 co-resident WGs.
//      FENCE-FREE cross-WG protocol: hbuf/flags accessed with sc0 sc1
//      (device-coherent at L3) relaxed ops only; no buffer_wbl2/inv ever.
//      U_f/U_o in 64KB XOR-swizzled LDS, U_c in 128 VGPRs.
// ---------------------------------------------------------------------------

typedef __attribute__((ext_vector_type(4))) float f32x4;
typedef __attribute__((ext_vector_type(8))) __bf16 bf16x8;
typedef __attribute__((ext_vector_type(2))) unsigned long long u64x2;

#define S_LEN 512
#define B_SZ  64
#define H_SZ  1024
#define I_SZ  1024
#define NWG   64

// ---- workspace layout (bytes) ----
#define OFF_WF  0
#define OFF_WO  2097152
#define OFF_WC  4194304
#define OFF_UF  6291456
#define OFF_UO  8388608
#define OFF_UC  10485760
#define OFF_GF  12582912
#define OFF_GO  79691776
#define OFF_GC  146800640
#define OFF_HB  213909504   // 2 * 64 * 1024 * 2 bytes = 262144
#define OFF_FLG 214171648   // 64 flags * 128B stride = 8192 bytes
#define FLG_STRIDE 32       // in u32 units (128 bytes)

__device__ __forceinline__ unsigned short f2bf(float f) {
  unsigned u = __float_as_uint(f);
  u += 0x7FFFu + ((u >> 16) & 1u);   // RNE (inputs finite)
  return (unsigned short)(u >> 16);
}
__device__ __forceinline__ float bf2f(unsigned short h) {
  return __uint_as_float(((unsigned)h) << 16);
}
__device__ __forceinline__ unsigned pack2(float lo, float hi) {
  return (unsigned)f2bf(lo) | ((unsigned)f2bf(hi) << 16);
}
__device__ __forceinline__ float sigmoid_f(float x) {
  return 1.f / (1.f + __expf(-x));
}
__device__ __forceinline__ float tanh_f(float x) {
  float xc = fminf(fmaxf(x, -15.f), 15.f);
  float e = __expf(-2.f * xc);       // in (0, e^30], finite
  return (1.f - e) / (1.f + e);
}

// device-coherent 2B store (bypasses L1/L2, lands in L3) — NOT compiler-tracked;
// must be followed by explicit s_waitcnt vmcnt(0) before signaling.
__device__ __forceinline__ void st_u16_sys(unsigned short* p, unsigned v) {
  asm volatile("global_store_short %0, %1, off sc0 sc1" :: "v"(p), "v"(v) : "memory");
}

// ---------------------------------------------------------------------------
// Six fp32->bf16 converts in one launch. grid (128, 6), 256 thr.
// ---------------------------------------------------------------------------
__global__ __launch_bounds__(256) void cvt6(
    const float4* __restrict__ s0, const float4* __restrict__ s1,
    const float4* __restrict__ s2, const float4* __restrict__ s3,
    const float4* __restrict__ s4, const float4* __restrict__ s5,
    ushort4* __restrict__ d0, ushort4* __restrict__ d1,
    ushort4* __restrict__ d2, ushort4* __restrict__ d3,
    ushort4* __restrict__ d4, ushort4* __restrict__ d5, int n4) {
  const float4* in; ushort4* out;
  switch (blockIdx.y) {
    case 0: in = s0; out = d0; break;
    case 1: in = s1; out = d1; break;
    case 2: in = s2; out = d2; break;
    case 3: in = s3; out = d3; break;
    case 4: in = s4; out = d4; break;
    default: in = s5; out = d5; break;
  }
  int i = blockIdx.x * 256 + threadIdx.x;
  const int stride = gridDim.x * 256;
  for (; i < n4; i += stride) {
    float4 v = in[i];
    ushort4 o;
    o.x = f2bf(v.x); o.y = f2bf(v.y); o.z = f2bf(v.z); o.w = f2bf(v.w);
    out[i] = o;
  }
}

// ---------------------------------------------------------------------------
// G[s*64+b][j] = sum_k x[b*512+s][k] * W[j][k] + bias[j]   (bf16 out)
// 128x128 tile, BK=32, 4 waves (2x2), reg-staged LDS. grid (8,256,3).
// ---------------------------------------------------------------------------
__global__ __launch_bounds__(256) void gemm_xw(
    const float* __restrict__ Xf,              // [32768][1024] fp32
    const unsigned short* __restrict__ W0,
    const unsigned short* __restrict__ W1,
    const unsigned short* __restrict__ W2,
    const float* __restrict__ bias0,
    const float* __restrict__ bias1,
    const float* __restrict__ bias2,
    unsigned short* __restrict__ G0,
    unsigned short* __restrict__ G1,
    unsigned short* __restrict__ G2)
{
  const int z = blockIdx.z;
  const unsigned short* W = (z == 0) ? W0 : (z == 1) ? W1 : W2;
  const float* bias        = (z == 0) ? bias0 : (z == 1) ? bias1 : bias2;
  unsigned short* G        = (z == 0) ? G0 : (z == 1) ? G1 : G2;

  const int m0 = blockIdx.y * 128;
  const int n0 = blockIdx.x * 128;
  const int tid = threadIdx.x;
  const int w = tid >> 6, l = tid & 63;
  const int lj = l & 15, lk = l >> 4;
  const int wm = w >> 1, wn = w & 1;

  __shared__ alignas(16) unsigned short As[128 * 32];  // 8 KB
  __shared__ alignas(16) unsigned short Bs[128 * 32];  // 8 KB

  f32x4 acc[4][4];
#pragma unroll
  for (int a = 0; a < 4; ++a)
#pragma unroll
    for (int q = 0; q < 4; ++q) acc[a][q] = (f32x4){0.f, 0.f, 0.f, 0.f};

  const int o1 = tid * 16;
  const int o2 = o1 + 4096;
  const int r1 = o1 >> 6, c1 = (o1 & 63) >> 1;
  const int r2 = o2 >> 6, c2 = (o2 & 63) >> 1;

  for (int kt = 0; kt < I_SZ; kt += 32) {
    const float* xa = Xf + (size_t)(m0 + r1) * I_SZ + kt + c1;
    const float* xb = Xf + (size_t)(m0 + r2) * I_SZ + kt + c2;
    float4 x0 = *(const float4*)xa;
    float4 x1 = *(const float4*)(xa + 4);
    float4 x2 = *(const float4*)xb;
    float4 x3 = *(const float4*)(xb + 4);
    uint4 wv0 = *(const uint4*)(W + (size_t)(n0 + r1) * I_SZ + kt + c1);
    uint4 wv1 = *(const uint4*)(W + (size_t)(n0 + r2) * I_SZ + kt + c2);

    uint4 a0, a1;
    a0.x = pack2(x0.x, x0.y); a0.y = pack2(x0.z, x0.w);
    a0.z = pack2(x1.x, x1.y); a0.w = pack2(x1.z, x1.w);
    a1.x = pack2(x2.x, x2.y); a1.y = pack2(x2.z, x2.w);
    a1.z = pack2(x3.x, x3.y); a1.w = pack2(x3.z, x3.w);

    __syncthreads();
    *(uint4*)((char*)As + o1) = a0;
    *(uint4*)((char*)As + o2) = a1;
    *(uint4*)((char*)Bs + o1) = wv0;
    *(uint4*)((char*)Bs + o2) = wv1;
    __syncthreads();

    bf16x8 af[4], bfg[4];
#pragma unroll
    for (int mi = 0; mi < 4; ++mi)
      af[mi] = *(const bf16x8*)(As + (wm * 64 + mi * 16 + lj) * 32 + lk * 8);
#pragma unroll
    for (int ni = 0; ni < 4; ++ni)
      bfg[ni] = *(const bf16x8*)(Bs + (wn * 64 + ni * 16 + lj) * 32 + lk * 8);
#pragma unroll
    for (int mi = 0; mi < 4; ++mi)
#pragma unroll
      for (int ni = 0; ni < 4; ++ni)
        acc[mi][ni] = __builtin_amdgcn_mfma_f32_16x16x32_bf16(af[mi], bfg[ni], acc[mi][ni], 0, 0, 0);
  }

#pragma unroll
  for (int ni = 0; ni < 4; ++ni) {
    const int j = n0 + wn * 64 + ni * 16 + lj;
    const float bb = bias[j];
#pragma unroll
    for (int mi = 0; mi < 4; ++mi) {
#pragma unroll
      for (int r = 0; r < 4; ++r) {
        const int m = m0 + wm * 64 + mi * 16 + lk * 4 + r;
        const int s = m & (S_LEN - 1);
        const int b = m >> 9;
        G[(size_t)(s * B_SZ + b) * H_SZ + j] = f2bf(acc[mi][ni][r] + bb);
      }
    }
  }
}

// ---------------------------------------------------------------------------
// Recurrent scan, fence-free. 64 WGs x 256 thr (4 waves), co-resident.
// WG wg owns H-cols [wg*16, wg*16+16) of all 3 gates; wave w owns batch rows
// [16w, 16w+16). U_f/U_o in 64KB swizzled LDS, U_c in 128 VGPRs, c in regs.
// hbuf (bf16, double-buffered) + flags accessed ONLY via sc0sc1 relaxed ops.
// ---------------------------------------------------------------------------
__global__ __launch_bounds__(256, 1) void lstm_scan(
    const unsigned short* __restrict__ Gf,
    const unsigned short* __restrict__ Go,
    const unsigned short* __restrict__ Gc,
    const unsigned short* __restrict__ Uf,
    const unsigned short* __restrict__ Uo,
    const unsigned short* __restrict__ Uc,
    unsigned short* __restrict__ hbuf,   // [2][64][1024] bf16 (zeroed)
    float* __restrict__ out,             // [64][512][1024] ++ h[64][1024] ++ c[64][1024]
    unsigned* __restrict__ flags)        // [64] stride 32 u32 (zeroed)
{
  const int wg = blockIdx.x;          // 0..63
  const int j0 = wg * 16;
  const int tid = threadIdx.x;
  const int w = tid >> 6, l = tid & 63;
  const int lj = l & 15, lk = l >> 4;
  const int j = j0 + lj;              // this lane's output column
  const int brow0 = w * 16 + lk * 4;  // D rows base (batch)

  __shared__ alignas(16) unsigned char UsB[65536];  // U_f | U_o, swizzled

  // ---- stage U_f, U_o into LDS (XOR swizzle: byte-in-row ^= (row&7)<<4) ----
  for (int idx = tid; idx < 2 * 16 * 128; idx += 256) {
    const int g  = idx >> 11;          // 0 = f, 1 = o
    const int r  = (idx >> 7) & 15;    // row (column j0+r of U)
    const int c8 = idx & 127;          // 16B chunk in row
    const unsigned short* src = (g ? Uo : Uf) + (size_t)(j0 + r) * H_SZ + c8 * 8;
    uint4 v = *(const uint4*)src;
    *(uint4*)(UsB + g * 32768 + r * 2048 + ((c8 * 16) ^ ((r & 7) << 4))) = v;
  }

  // ---- U_c fragments in registers (32 x bf16x8 = 128 VGPRs) ----
  bf16x8 bc[32];
  {
    const unsigned short* Ur = Uc + (size_t)j * H_SZ + lk * 8;
#pragma unroll
    for (int ks = 0; ks < 32; ++ks) bc[ks] = *(const bf16x8*)(Ur + ks * 32);
  }
  __syncthreads();

  // per-lane swizzled LDS read bases (row = lj)
  const int base45 = (lk * 16) ^ ((lj & 3) << 4);
  const int kxor   = ((lj >> 2) & 1) << 6;
  const unsigned char* Ufl = UsB + lj * 2048 + base45;
  const unsigned char* Uol = Ufl + 32768;

  float cst[4] = {0.f, 0.f, 0.f, 0.f};

  float gf[4], go_[4], gc_[4];
#pragma unroll
  for (int r = 0; r < 4; ++r) {
    const size_t gi = (size_t)(brow0 + r) * H_SZ + j;     // t = 0
    gf[r] = bf2f(Gf[gi]); go_[r] = bf2f(Go[gi]); gc_[r] = bf2f(Gc[gi]);
  }

  const size_t hoff = (size_t)B_SZ * S_LEN * H_SZ;        // 33554432
  const size_t coff = hoff + (size_t)B_SZ * H_SZ;

#pragma unroll 1
  for (int t = 0; t < S_LEN; ++t) {
    const unsigned short* hr = hbuf + (size_t)(t & 1) * (B_SZ * H_SZ)
                                    + (size_t)(w * 16 + lj) * H_SZ + lk * 8;

    f32x4 p0 = {0.f, 0.f, 0.f, 0.f};
    f32x4 p1 = {0.f, 0.f, 0.f, 0.f};
    f32x4 p2 = {0.f, 0.f, 0.f, 0.f};
#pragma unroll
    for (int ks = 0; ks < 32; ++ks) {
      const unsigned short* hp = hr + ks * 32;
      unsigned long long q0 = __hip_atomic_load((const unsigned long long*)hp,
                                __ATOMIC_RELAXED, __HIP_MEMORY_SCOPE_SYSTEM);
      unsigned long long q1 = __hip_atomic_load((const unsigned long long*)(hp + 4),
                                __ATOMIC_RELAXED, __HIP_MEMORY_SCOPE_SYSTEM);
      u64x2 qq; qq.x = q0; qq.y = q1;
      bf16x8 a = __builtin_bit_cast(bf16x8, qq);
      const int ko = (ks * 64) ^ kxor;
      bf16x8 bf_ = *(const bf16x8*)(Ufl + ko);
      bf16x8 bo_ = *(const bf16x8*)(Uol + ko);
      p0 = __builtin_amdgcn_mfma_f32_16x16x32_bf16(a, bf_,    p0, 0, 0, 0);
      p1 = __builtin_amdgcn_mfma_f32_16x16x32_bf16(a, bo_,    p1, 0, 0, 0);
      p2 = __builtin_amdgcn_mfma_f32_16x16x32_bf16(a, bc[ks], p2, 0, 0, 0);
    }

    // ---- elementwise gates + state update ----
    float hv[4];
#pragma unroll
    for (int r = 0; r < 4; ++r) {
      const float f  = sigmoid_f(p0[r] + gf[r]);
      const float o  = sigmoid_f(p1[r] + go_[r]);
      const float tc = tanh_f(p2[r] + gc_[r]);
      cst[r] = f * cst[r] + tc;
      hv[r] = o * cst[r];
    }

    if (t < S_LEN - 1) {
      // h -> hbuf[(t+1)&1] via device-coherent 2B stores
      unsigned short* hw = hbuf + (size_t)((t + 1) & 1) * (B_SZ * H_SZ);
#pragma unroll
      for (int r = 0; r < 4; ++r)
        st_u16_sys(&hw[(size_t)(brow0 + r) * H_SZ + j], (unsigned)f2bf(hv[r]));
      asm volatile("s_waitcnt vmcnt(0)" ::: "memory");   // stores ack'd at L3
      __syncthreads();                                    // all 4 waves done

      const unsigned target = (unsigned)(t + 1);
      if (tid == 0)
        __hip_atomic_store(&flags[wg * FLG_STRIDE], target,
                           __ATOMIC_RELAXED, __HIP_MEMORY_SCOPE_SYSTEM);

      // next step's gate pre-acts + out stores: latency hides under poll
#pragma unroll
      for (int r = 0; r < 4; ++r) {
        const size_t gi = ((size_t)(t + 1) * B_SZ + brow0 + r) * H_SZ + j;
        gf[r] = bf2f(Gf[gi]); go_[r] = bf2f(Go[gi]); gc_[r] = bf2f(Gc[gi]);
      }
#pragma unroll
      for (int r = 0; r < 4; ++r)
        __builtin_nontemporal_store(hv[r],
            &out[((size_t)(brow0 + r) * S_LEN + t) * H_SZ + j]);

      if (w == 0) {                      // wave0: 64 lanes poll 64 flags
        unsigned v;
        do {
          v = __hip_atomic_load(&flags[l * FLG_STRIDE],
                                __ATOMIC_RELAXED, __HIP_MEMORY_SCOPE_SYSTEM);
        } while (__any(v < target));
      }
      __builtin_amdgcn_fence(__ATOMIC_ACQUIRE, "workgroup");  // order, no cache ops
      __syncthreads();
    } else {
      // last step: outputs only, no barrier
#pragma unroll
      for (int r = 0; r < 4; ++r) {
        const int b = brow0 + r;
        __builtin_nontemporal_store(hv[r],
            &out[((size_t)b * S_LEN + t) * H_SZ + j]);
        out[hoff + (size_t)b * H_SZ + j] = hv[r];
        out[coff + (size_t)b * H_SZ + j] = cst[r];
      }
    }
  }
}

// ---------------------------------------------------------------------------
extern "C" void kernel_launch(void* const* d_in, const int* in_sizes, int n_in,
                              void* d_out, int out_size, void* d_ws, size_t ws_size,
                              hipStream_t stream) {
  const float* x   = (const float*)d_in[0];
  const float* W_f = (const float*)d_in[1];
  const float* U_f = (const float*)d_in[2];
  const float* b_f = (const float*)d_in[3];
  // d_in[4..6] = W_i, U_i, b_i : unused by the reference's output
  const float* W_o = (const float*)d_in[7];
  const float* U_o = (const float*)d_in[8];
  const float* b_o = (const float*)d_in[9];
  const float* W_c = (const float*)d_in[10];
  const float* U_c = (const float*)d_in[11];
  const float* b_c = (const float*)d_in[12];

  char* ws = (char*)d_ws;
  unsigned short* Wfb = (unsigned short*)(ws + OFF_WF);
  unsigned short* Wob = (unsigned short*)(ws + OFF_WO);
  unsigned short* Wcb = (unsigned short*)(ws + OFF_WC);
  unsigned short* Ufb = (unsigned short*)(ws + OFF_UF);
  unsigned short* Uob = (unsigned short*)(ws + OFF_UO);
  unsigned short* Ucb = (unsigned short*)(ws + OFF_UC);
  unsigned short* Gf  = (unsigned short*)(ws + OFF_GF);
  unsigned short* Go  = (unsigned short*)(ws + OFF_GO);
  unsigned short* Gc  = (unsigned short*)(ws + OFF_GC);
  unsigned short* hb  = (unsigned short*)(ws + OFF_HB);
  unsigned* flg       = (unsigned*)(ws + OFF_FLG);

  const int wn4 = (H_SZ * I_SZ) / 4;   // 262144
  dim3 cg(128, 6);
  cvt6<<<cg, 256, 0, stream>>>(
      (const float4*)W_f, (const float4*)W_o, (const float4*)W_c,
      (const float4*)U_f, (const float4*)U_o, (const float4*)U_c,
      (ushort4*)Wfb, (ushort4*)Wob, (ushort4*)Wcb,
      (ushort4*)Ufb, (ushort4*)Uob, (ushort4*)Ucb, wn4);

  // zero h double-buffer + barrier flags (ws is poisoned each call)
  hipMemsetAsync(ws + OFF_HB, 0, 262144 + 8192, stream);

  dim3 gg(8, 256, 3);
  gemm_xw<<<gg, 256, 0, stream>>>(x, Wfb, Wob, Wcb, b_f, b_o, b_c, Gf, Go, Gc);

  lstm_scan<<<NWG, 256, 0, stream>>>(Gf, Go, Gc, Ufb, Uob, Ucb, hb,
                                     (float*)d_out, flg);
}